// Round 6
// baseline (140.445 us; speedup 1.0000x reference)
//
#include <hip/hip_runtime.h>

#define T_TEST 8192
#define BB 8
#define FF 100
#define HH 512

typedef __bf16 bf16x8 __attribute__((ext_vector_type(8)));
typedef float f32x16 __attribute__((ext_vector_type(16)));
typedef unsigned short u16;
typedef unsigned int u32;

__device__ __forceinline__ u16 f2bf(float f) {
    u32 u = __float_as_uint(f);
    u += 0x7fffu + ((u >> 16) & 1);   // RNE
    return (u16)(u >> 16);
}

__device__ __forceinline__ float nan2num(float v) {
    u32 u = __float_as_uint(v);
    if ((u & 0x7f800000u) == 0x7f800000u) {
        v = (u & 0x007fffffu) ? 0.f : ((u >> 31) ? -3.3895314e38f : 3.3895314e38f);
    }
    return v;
}

// ---- combined weight prep: 32x32x16 fragment-major layouts -------------
// B-frag for 32x32x16: B[k][n], n = lane&31, k = (lane>>5)*8 + j, 8 bf16/lane.
// w1f frag idx: ((b*8  + ks)*16 + n32)*64 + lane   (K=128 padded -> ks 0..7)
// w2f frag idx: ((b*32 + ks)*16 + n32)*64 + lane   (K=512        -> ks 0..31)
__global__ void prep_w(const float* __restrict__ w1, const float* __restrict__ w2,
                       u16* __restrict__ w1f, u16* __restrict__ w2f) {
    int bid = blockIdx.x;
    if (bid < 256) {                      // w1f: 65536 threads
        int t = bid * 256 + threadIdx.x;
        int lane = t & 63;
        int n32 = (t >> 6) & 15;
        int b = t >> 13;
        int n = n32 * 32 + (lane & 31);
        int kb = ((t >> 10) & 7) * 16 + (lane >> 5) * 8;
        u32 p[4];
#pragma unroll
        for (int jp = 0; jp < 4; ++jp) {
            int k0 = kb + jp * 2;
            float v0 = (k0 < FF)     ? w1[(b * FF + k0) * HH + n]     : 0.f;
            float v1 = (k0 + 1 < FF) ? w1[(b * FF + k0 + 1) * HH + n] : 0.f;
            p[jp] = (u32)f2bf(v0) | ((u32)f2bf(v1) << 16);
        }
        uint4 o = {p[0], p[1], p[2], p[3]};
        *(uint4*)(w1f + (size_t)t * 8) = o;   // t == frag index by construction
    } else {                              // w2f: 262144 threads
        int t = (bid - 256) * 256 + threadIdx.x;
        int lane = t & 63;
        int n32 = (t >> 6) & 15;
        int b = t >> 15;
        int n = n32 * 32 + (lane & 31);
        int kb = ((t >> 10) & 31) * 16 + (lane >> 5) * 8;
        u32 p[4];
#pragma unroll
        for (int jp = 0; jp < 4; ++jp) {
            int k0 = kb + jp * 2;
            float v0 = w2[(b * HH + k0) * HH + n];
            float v1 = w2[(b * HH + k0 + 1) * HH + n];
            p[jp] = (u32)f2bf(v0) | ((u32)f2bf(v1) << 16);
        }
        uint4 o = {p[0], p[1], p[2], p[3]};
        *(uint4*)(w2f + (size_t)t * 8) = o;
    }
}

// swizzled LDS indices: granule = 8 u16 = 16B; xor low-4 granule bits by row&15.
__device__ __forceinline__ int x_idx(int row, int k) {     // [64][128] bf16
    int g = k >> 3;
    int gp = g ^ (row & 15);               // 16 granules/row
    return row * 128 + gp * 8 + (k & 7);
}
__device__ __forceinline__ int h1_idx(int row, int col) {  // [64][512] bf16
    int g = col >> 3;
    int gp = (g & ~15) | ((g ^ row) & 15); // 64 granules/row
    return row * 512 + gp * 8 + (col & 7);
}

// ---- fused 3-layer MLP: 64 rows/block, 8 waves n-sliced (64 cols each),
// ---- 32x32x16 MFMA, depth-3 SW pipeline on A+B, wave K-phase stagger ----
__global__ __launch_bounds__(512, 4) void fused_mlp(
    const float* __restrict__ x, const u16* __restrict__ w1f,
    const float* __restrict__ b1, const u16* __restrict__ w2f,
    const float* __restrict__ b2, const float* __restrict__ w3,
    const float* __restrict__ b3, float* __restrict__ out) {
    __shared__ __align__(16) u16 h1_lds[64 * 512];   // 64 KB
    __shared__ __align__(16) u16 x_lds[64 * 128];    // 16 KB (reused as part[])

    const int tid = threadIdx.x;
    const int b = blockIdx.x;              // batch -> XCD affinity
    const int m0 = blockIdx.y * 64;
    const int lane = tid & 63;
    const int w = tid >> 6;                // wave 0..7 owns cols w*64..+64
    const int l31 = lane & 31, lh = lane >> 5;
    const int n32b = w * 2;
    const int r1 = w;                      // layer-1 K-phase (mod 8)
    const int r2 = (w * 4) & 31;           // layer-2 K-phase (mod 32)

    const bf16x8* W1 = (const bf16x8*)w1f + (size_t)b * (8 * 16 * 64);
    const bf16x8* W2 = (const bf16x8*)w2f + (size_t)b * (32 * 16 * 64);

    bf16x8 aa[3][2], bb[3][2];

    // layer-1 B prologue (stages 0,1) — in flight across x staging
    {
        int k0 = r1, k1 = (r1 + 1) & 7;
        bb[0][0] = W1[(k0 * 16 + n32b + 0) * 64 + lane];
        bb[0][1] = W1[(k0 * 16 + n32b + 1) * 64 + lane];
        bb[1][0] = W1[(k1 * 16 + n32b + 0) * 64 + lane];
        bb[1][1] = W1[(k1 * 16 + n32b + 1) * 64 + lane];
    }

    // ---- stage x: 8 threads/row, bf16, swizzled, k 100..127 zeroed ----
    {
        int row = tid >> 3, sub = tid & 7;
        const float* xr = x + ((size_t)(m0 + row) * BB + b) * FF;
        float4 v0 = *(const float4*)(xr + sub * 4);
        float4 v1 = *(const float4*)(xr + 32 + sub * 4);
        float4 v2 = *(const float4*)(xr + 64 + sub * 4);
        auto xw = [&](int k, float4 v) {
            ushort4 h;
            h.x = f2bf(nan2num(v.x));
            h.y = f2bf(nan2num(v.y));
            h.z = f2bf(nan2num(v.z));
            h.w = f2bf(nan2num(v.w));
            *(ushort4*)(&x_lds[x_idx(row, k)]) = h;
        };
        xw(sub * 4, v0);
        xw(32 + sub * 4, v1);
        xw(64 + sub * 4, v2);
        if (sub == 0) {
            float4 v3 = *(const float4*)(xr + 96);
            xw(96, v3);                                   // k 96..99
            ushort4 z = {0, 0, 0, 0};
            *(ushort4*)(&x_lds[x_idx(row, 100)]) = z;     // k 100..103
        } else if (sub <= 3) {
            int4 z = {0, 0, 0, 0};
            *(int4*)(&x_lds[x_idx(row, 96 + sub * 8)]) = z;   // k 104..127
        }
    }
    __syncthreads();

    // ---- layer 1: depth-3 pipelined, K-phase r1 ----
    f32x16 acc1[2][2] = {};
    {
        int k0 = r1, k1 = (r1 + 1) & 7;
        aa[0][0] = *(const bf16x8*)(&x_lds[x_idx(l31,      (2 * k0 + lh) * 8)]);
        aa[0][1] = *(const bf16x8*)(&x_lds[x_idx(32 + l31, (2 * k0 + lh) * 8)]);
        aa[1][0] = *(const bf16x8*)(&x_lds[x_idx(l31,      (2 * k1 + lh) * 8)]);
        aa[1][1] = *(const bf16x8*)(&x_lds[x_idx(32 + l31, (2 * k1 + lh) * 8)]);
    }
#pragma unroll
    for (int ks = 0; ks < 8; ++ks) {
        const int p = ks % 3;
        if (ks < 6) {
            const int f = (ks + 2) % 3;
            int ksp = (ks + 2 + r1) & 7;
            aa[f][0] = *(const bf16x8*)(&x_lds[x_idx(l31,      (2 * ksp + lh) * 8)]);
            aa[f][1] = *(const bf16x8*)(&x_lds[x_idx(32 + l31, (2 * ksp + lh) * 8)]);
            bb[f][0] = W1[(ksp * 16 + n32b + 0) * 64 + lane];
            bb[f][1] = W1[(ksp * 16 + n32b + 1) * 64 + lane];
        }
        acc1[0][0] = __builtin_amdgcn_mfma_f32_32x32x16_bf16(aa[p][0], bb[p][0], acc1[0][0], 0, 0, 0);
        acc1[0][1] = __builtin_amdgcn_mfma_f32_32x32x16_bf16(aa[p][0], bb[p][1], acc1[0][1], 0, 0, 0);
        acc1[1][0] = __builtin_amdgcn_mfma_f32_32x32x16_bf16(aa[p][1], bb[p][0], acc1[1][0], 0, 0, 0);
        acc1[1][1] = __builtin_amdgcn_mfma_f32_32x32x16_bf16(aa[p][1], bb[p][1], acc1[1][1], 0, 0, 0);
    }

    // layer-2 B prologue — in flight across epilogue-1 + barrier
    {
        int k0 = r2, k1 = (r2 + 1) & 31;
        bb[0][0] = W2[(k0 * 16 + n32b + 0) * 64 + lane];
        bb[0][1] = W2[(k0 * 16 + n32b + 1) * 64 + lane];
        bb[1][0] = W2[(k1 * 16 + n32b + 0) * 64 + lane];
        bb[1][1] = W2[(k1 * 16 + n32b + 1) * 64 + lane];
    }

    // ---- epilogue 1: relu(acc1+b1) -> h1_lds (paired dword writes) ----
    // C/D layout 32x32: col = lane&31, row = (r&3) + 8*(r>>2) + 4*(lane>>5)
    {
        u32* h32 = (u32*)h1_lds;
        const float* b1g = b1 + b * HH;
#pragma unroll
        for (int ni = 0; ni < 2; ++ni) {
            int n = (n32b + ni) * 32 + l31;
            float b1v = b1g[n];
            int ncol = n & ~1;
#pragma unroll
            for (int mi = 0; mi < 2; ++mi)
#pragma unroll
                for (int qd = 0; qd < 4; ++qd) {
                    u32 own01 = (u32)f2bf(fmaxf(acc1[mi][ni][qd * 4 + 0] + b1v, 0.f)) |
                                ((u32)f2bf(fmaxf(acc1[mi][ni][qd * 4 + 1] + b1v, 0.f)) << 16);
                    u32 own23 = (u32)f2bf(fmaxf(acc1[mi][ni][qd * 4 + 2] + b1v, 0.f)) |
                                ((u32)f2bf(fmaxf(acc1[mi][ni][qd * 4 + 3] + b1v, 0.f)) << 16);
                    u32 oth01 = __shfl_xor(own01, 1, 64);
                    u32 oth23 = __shfl_xor(own23, 1, 64);
                    int row0 = mi * 32 + qd * 8 + lh * 4;
                    if (!(lane & 1)) {
                        u32 d0 = (own01 & 0xffffu) | (oth01 << 16);
                        u32 d1 = (own01 >> 16) | (oth01 & 0xffff0000u);
                        h32[h1_idx(row0, ncol) >> 1] = d0;
                        h32[h1_idx(row0 + 1, ncol) >> 1] = d1;
                    } else {
                        u32 d2 = (oth23 & 0xffffu) | (own23 << 16);
                        u32 d3 = (oth23 >> 16) | (own23 & 0xffff0000u);
                        h32[h1_idx(row0 + 2, ncol) >> 1] = d2;
                        h32[h1_idx(row0 + 3, ncol) >> 1] = d3;
                    }
                }
        }
    }
    __syncthreads();   // h1 visible to all waves

    // ---- layer 2: full k=512, depth-3 pipelined, K-phase r2 ----
    f32x16 acc2[2][2] = {};
    {
        int k0 = r2, k1 = (r2 + 1) & 31;
        aa[0][0] = *(const bf16x8*)(&h1_lds[h1_idx(l31,      (2 * k0 + lh) * 8)]);
        aa[0][1] = *(const bf16x8*)(&h1_lds[h1_idx(32 + l31, (2 * k0 + lh) * 8)]);
        aa[1][0] = *(const bf16x8*)(&h1_lds[h1_idx(l31,      (2 * k1 + lh) * 8)]);
        aa[1][1] = *(const bf16x8*)(&h1_lds[h1_idx(32 + l31, (2 * k1 + lh) * 8)]);
    }
#pragma unroll
    for (int ks = 0; ks < 32; ++ks) {
        const int p = ks % 3;
        if (ks < 30) {
            const int f = (ks + 2) % 3;
            int ksp = (ks + 2 + r2) & 31;
            aa[f][0] = *(const bf16x8*)(&h1_lds[h1_idx(l31,      (2 * ksp + lh) * 8)]);
            aa[f][1] = *(const bf16x8*)(&h1_lds[h1_idx(32 + l31, (2 * ksp + lh) * 8)]);
            bb[f][0] = W2[(ksp * 16 + n32b + 0) * 64 + lane];
            bb[f][1] = W2[(ksp * 16 + n32b + 1) * 64 + lane];
        }
        acc2[0][0] = __builtin_amdgcn_mfma_f32_32x32x16_bf16(aa[p][0], bb[p][0], acc2[0][0], 0, 0, 0);
        acc2[0][1] = __builtin_amdgcn_mfma_f32_32x32x16_bf16(aa[p][0], bb[p][1], acc2[0][1], 0, 0, 0);
        acc2[1][0] = __builtin_amdgcn_mfma_f32_32x32x16_bf16(aa[p][1], bb[p][0], acc2[1][0], 0, 0, 0);
        acc2[1][1] = __builtin_amdgcn_mfma_f32_32x32x16_bf16(aa[p][1], bb[p][1], acc2[1][1], 0, 0, 0);
    }

    // ---- layer 3: fold n-slice in-register, reduce over 32 cols ----
    const float* b2g = b2 + b * HH;
    const float* w3g = w3 + b * HH;
    float b2v0 = b2g[(n32b + 0) * 32 + l31], w3v0 = w3g[(n32b + 0) * 32 + l31];
    float b2v1 = b2g[(n32b + 1) * 32 + l31], w3v1 = w3g[(n32b + 1) * 32 + l31];
    float* part = (float*)x_lds;   // [8][64]; x dead (all reads pre-h1-barrier)
#pragma unroll
    for (int mi = 0; mi < 2; ++mi)
#pragma unroll
        for (int r = 0; r < 16; ++r) {
            float v = fmaxf(acc2[mi][0][r] + b2v0, 0.f) * w3v0 +
                      fmaxf(acc2[mi][1][r] + b2v1, 0.f) * w3v1;
            v += __shfl_xor(v, 1, 64);
            v += __shfl_xor(v, 2, 64);
            v += __shfl_xor(v, 4, 64);
            v += __shfl_xor(v, 8, 64);
            v += __shfl_xor(v, 16, 64);
            if (l31 == 0)
                part[w * 64 + mi * 32 + (r & 3) + 8 * (r >> 2) + 4 * lh] = v;
        }
    __syncthreads();
    if (tid < 64) {
        float s = b3[b];
#pragma unroll
        for (int ww = 0; ww < 8; ++ww) s += part[ww * 64 + tid];
        out[(size_t)(m0 + tid) * BB + b] = s;
    }
}

extern "C" void kernel_launch(void* const* d_in, const int* in_sizes, int n_in,
                              void* d_out, int out_size, void* d_ws, size_t ws_size,
                              hipStream_t stream) {
    const float* x  = (const float*)d_in[0];
    const float* w1 = (const float*)d_in[1];
    const float* b1 = (const float*)d_in[2];
    const float* w2 = (const float*)d_in[3];
    const float* b2 = (const float*)d_in[4];
    const float* w3 = (const float*)d_in[5];
    const float* b3 = (const float*)d_in[6];
    float* out = (float*)d_out;

    u16* w1f = (u16*)d_ws;                              // 8*8192 frags  = 1 MB
    u16* w2f = w1f + (size_t)BB * 8192 * 8;             // 8*32768 frags = 4 MB

    prep_w<<<1280, 256, 0, stream>>>(w1, w2, w1f, w2f);

    // grid.x = batch (XCD round-robin), grid.y = 64-row tile
    fused_mlp<<<dim3(BB, T_TEST / 64), 512, 0, stream>>>(
        x, w1f, b1, w2f, b2, w3, b3, out);
}